// Round 12
// baseline (282.948 us; speedup 1.0000x reference)
//
#include <hip/hip_runtime.h>
#include <math.h>

#define NN 50000
#define DD 128
#define HH 128
#define L1 64
#define L2 32
#define OO 10

typedef short v8s __attribute__((ext_vector_type(8)));   // 8 bf16 (4 VGPRs)
typedef float v4f __attribute__((ext_vector_type(4)));   // MFMA accumulator

// ---- bf16 helpers (manual: RNE pack) ----
__device__ __forceinline__ float bf2f_lo(unsigned u) { return __uint_as_float(u << 16); }
__device__ __forceinline__ float bf2f_hi(unsigned u) { return __uint_as_float(u & 0xffff0000u); }
__device__ __forceinline__ unsigned short f2bf(float f) {
    unsigned u = __float_as_uint(f);
    return (unsigned short)((u + 0x7fffu + ((u >> 16) & 1u)) >> 16);
}
__device__ __forceinline__ float gelu_f(float v) {
    return 0.5f * v * (1.f + erff(v * 0.70710678118654752f));
}

// ---------------- K0: transpose W, W1, W2 to bf16 B-operand layouts ----------
__global__ __launch_bounds__(256) void k_wprep(
    const float* __restrict__ W, const float* __restrict__ W1,
    const float* __restrict__ W2, unsigned short* __restrict__ wtb,
    unsigned short* __restrict__ w1tb, unsigned short* __restrict__ w2tb)
{
    int i = blockIdx.x * 256 + threadIdx.x;
    if (i < 128 * 136) {
        int n = i / 136, k = i % 136;
        wtb[i] = (k < DD) ? f2bf(W[k * HH + n]) : (unsigned short)0;
    } else if (i < 128 * 136 + 64 * 136) {
        int j = i - 128 * 136;
        int n = j / 136, k = j % 136;
        w1tb[j] = (k < HH) ? f2bf(W1[k * L1 + n]) : (unsigned short)0;
    } else if (i < 128 * 136 + 64 * 136 + 32 * 72) {
        int j = i - (128 * 136 + 64 * 136);
        int n = j / 72, k = j % 72;
        w2tb[j] = (k < L1) ? f2bf(W2[k * L2 + n]) : (unsigned short)0;
    }
}

// ---------------- K1: support = x @ W via bf16 MFMA (R9-passing structure) ----
// EMPIRICAL LAW (R10/R11 fails): MFMA operands must be LDS-staged on this
// toolchain — global-sourced fragments produced wrong numerics twice.
// Improvement vs R9 (bit-identical math): wt staged ONCE per block; grid-stride
// over row-tiles (512 blocks x ~3 tiles) re-staging only xs. 8 waves, 70 KB LDS.
__global__ __launch_bounds__(512, 2) void k_support(
    const float* __restrict__ x, const unsigned short* __restrict__ wtb,
    unsigned short* __restrict__ supb, int rows,
    const int* __restrict__ ei, int* __restrict__ counts, int E, int ntiles)
{
    __shared__ __align__(16) unsigned short xs[128 * 136];
    __shared__ __align__(16) unsigned short wt[128 * 136];
    const int tid = threadIdx.x;

    // stage W^T once per block
    for (int u = tid * 4; u < 128 * 136; u += 2048)
        *(uint2*)(&wt[u]) = *(const uint2*)(wtb + u);

    // fused dst-histogram (independent; hides under staging/MFMA)
    {
        const int chunk = (E + gridDim.x - 1) / gridDim.x;
        const int e0 = blockIdx.x * chunk;
        const int e1 = min(e0 + chunk, E);
        for (int e = e0 + tid; e < e1; e += 512)
            atomicAdd(&counts[ei[(size_t)E + e]], 1);
    }

    const int lane = tid & 63;
    const int w = tid >> 6;       // wave 0..7
    const int m0 = w * 16;        // wave's row base (tile-local)
    const int lm = lane & 15;
    const int q  = lane >> 4;     // 0..3

    for (int t = blockIdx.x; t < ntiles; t += gridDim.x) {
        const int row0 = t * 128;
        __syncthreads();   // xs from previous tile fully consumed (also orders wt on iter 1)
        for (int u = tid * 4; u < 128 * DD; u += 2048) {
            const int r = u >> 7, c = u & 127;
            float4 v = make_float4(0.f, 0.f, 0.f, 0.f);
            if (row0 + r < rows) v = *(const float4*)(x + (size_t)(row0 + r) * DD + c);
            ushort4 o;
            o.x = f2bf(v.x); o.y = f2bf(v.y); o.z = f2bf(v.z); o.w = f2bf(v.w);
            *(ushort4*)(&xs[r * 136 + c]) = o;
        }
        __syncthreads();

        v4f acc[8];
        #pragma unroll
        for (int i = 0; i < 8; ++i) acc[i] = (v4f)(0.f);

        #pragma unroll
        for (int ks = 0; ks < 4; ++ks) {
            const int k0 = ks * 32 + q * 8;
            const v8s af = *(const v8s*)(&xs[(m0 + lm) * 136 + k0]);
            #pragma unroll
            for (int ct = 0; ct < 8; ++ct) {
                const v8s bf = *(const v8s*)(&wt[(ct * 16 + lm) * 136 + k0]);
                acc[ct] = __builtin_amdgcn_mfma_f32_16x16x32_bf16(af, bf, acc[ct], 0, 0, 0);
            }
        }

        // C/D: col = ct*16 + lm, row = q*4 + reg  [m89-verified]
        #pragma unroll
        for (int ct = 0; ct < 8; ++ct) {
            const int col = ct * 16 + lm;
            #pragma unroll
            for (int r = 0; r < 4; ++r) {
                const int rowg = row0 + m0 + q * 4 + r;
                if (rowg < rows) {
                    const int b = (rowg >= NN) ? 1 : 0;
                    const int n = rowg - b * NN;
                    supb[((size_t)n * 2 + b) * HH + col] = f2bf(acc[ct][r]);
                }
            }
        }
    }
}

// ---------------- multi-block scan, stage 1 ----------------
__global__ __launch_bounds__(1024) void k_scan1(
    const int* __restrict__ counts, int* __restrict__ offsets,
    int* __restrict__ blksum, int n)
{
    __shared__ int wsum[16], woff[16];
    const int tid = threadIdx.x, lane = tid & 63, wv = tid >> 6;
    const int i = blockIdx.x * 1024 + tid;
    int v = (i < n) ? counts[i] : 0;
    int x = v;
    #pragma unroll
    for (int d = 1; d < 64; d <<= 1) { int t = __shfl_up(x, d); if (lane >= d) x += t; }
    if (lane == 63) wsum[wv] = x;
    __syncthreads();
    if (wv == 0 && lane < 16) {
        int y = wsum[lane];
        #pragma unroll
        for (int d = 1; d < 16; d <<= 1) { int t = __shfl_up(y, d); if (lane >= d) y += t; }
        woff[lane] = y - wsum[lane];
        if (lane == 15) blksum[blockIdx.x] = y;
    }
    __syncthreads();
    if (i < n) offsets[i] = woff[wv] + (x - v);
}

// ---------------- multi-block scan, stage 2 ----------------
__global__ __launch_bounds__(1024) void k_scan2(
    int* __restrict__ offsets, const int* __restrict__ blksum, int nblk, int n)
{
    __shared__ int base_sh, tot_sh;
    const int tid = threadIdx.x, lane = tid & 63, wv = tid >> 6;
    if (wv == 0) {
        int v = (lane < nblk) ? blksum[lane] : 0;
        int x = v;
        #pragma unroll
        for (int d = 1; d < 64; d <<= 1) { int t = __shfl_up(x, d); if (lane >= d) x += t; }
        int incl = __shfl(x, blockIdx.x);
        int own  = __shfl(v, blockIdx.x);
        int tot  = __shfl(x, nblk - 1);
        if (lane == 0) { base_sh = incl - own; tot_sh = tot; }
    }
    __syncthreads();
    const int i = blockIdx.x * 1024 + tid;
    if (i < n) offsets[i] += base_sh;
    if (blockIdx.x == nblk - 1 && tid == 0) offsets[n] = tot_sh;
}

// ---------------- CSR build: bucket src indices by dst ----------------
__global__ __launch_bounds__(256) void k_bucket(
    const int* __restrict__ ei, const int* __restrict__ offsets,
    int* __restrict__ cursor, int* __restrict__ ss, int E)
{
    int e = blockIdx.x * 256 + threadIdx.x;
    if (e < E) {
        int d = ei[E + e];
        int pos = offsets[d] + atomicAdd(&cursor[d], 1);
        ss[pos] = ei[e];
    }
}

// ---------------- K2: gather-aggregate over interleaved bf16 rows -------------
__global__ __launch_bounds__(256) void k_agg(
    const unsigned short* __restrict__ supb, const int* __restrict__ offsets,
    const int* __restrict__ ss, unsigned short* __restrict__ aggb, int nn)
{
    const int tid = threadIdx.x;
    const int lane = tid & 63;
    const int wv = tid >> 6;
    const int d = blockIdx.x * 4 + wv;
    if (d >= nn) return;
    const unsigned short* sp = supb + lane * 4;
    const int s0 = offsets[d], s1 = offsets[d + 1];
    float4 a = make_float4(0.f, 0.f, 0.f, 0.f);
    float4 a2 = make_float4(0.f, 0.f, 0.f, 0.f);
    int i = s0;
    for (; i + 4 <= s1; i += 4) {
        const int sA = ss[i], sB = ss[i + 1], sC = ss[i + 2], sD = ss[i + 3];
        const uint2 rA = *(const uint2*)(sp + (size_t)sA * 256);
        const uint2 rB = *(const uint2*)(sp + (size_t)sB * 256);
        const uint2 rC = *(const uint2*)(sp + (size_t)sC * 256);
        const uint2 rD = *(const uint2*)(sp + (size_t)sD * 256);
        a.x  += bf2f_lo(rA.x); a.y  += bf2f_hi(rA.x); a.z  += bf2f_lo(rA.y); a.w  += bf2f_hi(rA.y);
        a2.x += bf2f_lo(rB.x); a2.y += bf2f_hi(rB.x); a2.z += bf2f_lo(rB.y); a2.w += bf2f_hi(rB.y);
        a.x  += bf2f_lo(rC.x); a.y  += bf2f_hi(rC.x); a.z  += bf2f_lo(rC.y); a.w  += bf2f_hi(rC.y);
        a2.x += bf2f_lo(rD.x); a2.y += bf2f_hi(rD.x); a2.z += bf2f_lo(rD.y); a2.w += bf2f_hi(rD.y);
    }
    for (; i < s1; ++i) {
        const uint2 r = *(const uint2*)(sp + (size_t)ss[i] * 256);
        a.x += bf2f_lo(r.x); a.y += bf2f_hi(r.x); a.z += bf2f_lo(r.y); a.w += bf2f_hi(r.y);
    }
    a.x += a2.x; a.y += a2.y; a.z += a2.z; a.w += a2.w;
    ushort4 o;
    o.x = f2bf(a.x); o.y = f2bf(a.y); o.z = f2bf(a.z); o.w = f2bf(a.w);
    *(ushort4*)(aggb + (size_t)d * 256 + lane * 4) = o;
}

// ---------------- K3: gelu + MFMA MLP(128->64->32) + column sums --------------
__global__ __launch_bounds__(512, 6) void k_mlp(
    const unsigned short* __restrict__ aggb, const float* __restrict__ b0v,
    const unsigned short* __restrict__ w1tb, const float* __restrict__ b1v,
    const unsigned short* __restrict__ w2tb, const float* __restrict__ b2v,
    float* __restrict__ partials, int srows)
{
    __shared__ __align__(16) unsigned short wt1[64 * 136];
    __shared__ __align__(16) unsigned short wt2[32 * 72];
    __shared__ __align__(16) unsigned char upool[64 * 136 * 2];
    __shared__ __align__(16) unsigned short h1b[64 * 72];
    __shared__ float b0s[DD], b1s[L1], b2s[L2];
    __shared__ float oacc[64];
    unsigned short* hsb = (unsigned short*)upool;   // [64][136] bf16
    float* h2p = (float*)upool;                     // [64][36] f32 (after hsb dead)

    const int tid = threadIdx.x;
    const int row0 = blockIdx.x * 64;

    for (int u = tid * 4; u < 64 * 136; u += 2048)
        *(uint2*)(&wt1[u]) = *(const uint2*)(w1tb + u);
    for (int u = tid * 4; u < 32 * 72; u += 2048)
        *(uint2*)(&wt2[u]) = *(const uint2*)(w2tb + u);
    if (tid < DD) b0s[tid] = b0v[tid];
    if (tid < L1) b1s[tid] = b1v[tid];
    if (tid < L2) b2s[tid] = b2v[tid];
    if (tid < 64) oacc[tid] = 0.f;

    for (int u = tid * 8; u < 64 * DD; u += 4096) {
        const int r = u >> 7, c = u & 127;
        uint4 raw = make_uint4(0, 0, 0, 0);
        if (row0 + r < srows) raw = *(const uint4*)(aggb + (size_t)(row0 + r) * HH + c);
        float v[8];
        v[0] = bf2f_lo(raw.x) + b0s[c + 0]; v[1] = bf2f_hi(raw.x) + b0s[c + 1];
        v[2] = bf2f_lo(raw.y) + b0s[c + 2]; v[3] = bf2f_hi(raw.y) + b0s[c + 3];
        v[4] = bf2f_lo(raw.z) + b0s[c + 4]; v[5] = bf2f_hi(raw.z) + b0s[c + 5];
        v[6] = bf2f_lo(raw.w) + b0s[c + 6]; v[7] = bf2f_hi(raw.w) + b0s[c + 7];
        ushort4 o0, o1;
        o0.x = f2bf(gelu_f(v[0])); o0.y = f2bf(gelu_f(v[1]));
        o0.z = f2bf(gelu_f(v[2])); o0.w = f2bf(gelu_f(v[3]));
        o1.x = f2bf(gelu_f(v[4])); o1.y = f2bf(gelu_f(v[5]));
        o1.z = f2bf(gelu_f(v[6])); o1.w = f2bf(gelu_f(v[7]));
        *(ushort4*)(&hsb[r * 136 + c]) = o0;
        *(ushort4*)(&hsb[r * 136 + c + 4]) = o1;
    }
    __syncthreads();

    const int lane = tid & 63;
    const int w = tid >> 6;
    const int lm = lane & 15;
    const int q = lane >> 4;
    const int r1 = (w & 3) * 16;

    // layer1 (64x128 @ 128x64)
    {
        const int c1 = (w >> 2) * 32;
        v4f a1[2];
        a1[0] = (v4f)(0.f); a1[1] = (v4f)(0.f);
        #pragma unroll
        for (int ks = 0; ks < 4; ++ks) {
            const int k0 = ks * 32 + q * 8;
            const v8s af = *(const v8s*)(&hsb[(r1 + lm) * 136 + k0]);
            #pragma unroll
            for (int ct = 0; ct < 2; ++ct) {
                const v8s bf = *(const v8s*)(&wt1[(c1 + ct * 16 + lm) * 136 + k0]);
                a1[ct] = __builtin_amdgcn_mfma_f32_16x16x32_bf16(af, bf, a1[ct], 0, 0, 0);
            }
        }
        #pragma unroll
        for (int ct = 0; ct < 2; ++ct) {
            const int col = c1 + ct * 16 + lm;
            const float bias = b1s[col];
            #pragma unroll
            for (int r = 0; r < 4; ++r)
                h1b[(r1 + q * 4 + r) * 72 + col] = f2bf(fmaxf(a1[ct][r] + bias, 0.f));
        }
    }
    __syncthreads();

    // layer2 (64x64 @ 64x32)
    {
        const int c2 = (w >> 2) * 16;
        v4f a2 = (v4f)(0.f);
        #pragma unroll
        for (int ks = 0; ks < 2; ++ks) {
            const int k0 = ks * 32 + q * 8;
            const v8s af = *(const v8s*)(&h1b[(r1 + lm) * 72 + k0]);
            const v8s bf = *(const v8s*)(&wt2[(c2 + lm) * 72 + k0]);
            a2 = __builtin_amdgcn_mfma_f32_16x16x32_bf16(af, bf, a2, 0, 0, 0);
        }
        const int col = c2 + lm;
        const float bias = b2s[col];
        #pragma unroll
        for (int r = 0; r < 4; ++r)
            h2p[(r1 + q * 4 + r) * 36 + col] = fmaxf(a2[r] + bias, 0.f);
    }
    __syncthreads();

    // column sums: storage row r -> batch r&1
    {
        const int c = tid & 31;
        const int g = tid >> 5;
        float p0 = 0.f, p1 = 0.f;
        #pragma unroll
        for (int i = 0; i < 4; ++i) {
            const int r = g * 4 + i;
            if (row0 + r < srows) {
                const float v = h2p[r * 36 + c];
                if (r & 1) p1 += v; else p0 += v;
            }
        }
        if (p0 != 0.f) atomicAdd(&oacc[c], p0);
        if (p1 != 0.f) atomicAdd(&oacc[32 + c], p1);
    }
    __syncthreads();
    if (tid < 64) partials[(size_t)blockIdx.x * 64 + tid] = oacc[tid];
}

// ---------------- Fallback path (ws too small for CSR) ----------------
__global__ __launch_bounds__(256) void k_scatter(
    const int* __restrict__ ei, const unsigned short* __restrict__ supb,
    float* __restrict__ aggf, int E)
{
    const int tid = threadIdx.x;
    const int eg = tid >> 6;
    const int lane = tid & 63;
    const int e = blockIdx.x * 4 + eg;
    if (e >= E) return;
    const int src = ei[e];
    const int dst = ei[E + e];
    const uint2 r = *(const uint2*)(supb + (size_t)src * 256 + lane * 4);
    float* ap = aggf + (size_t)dst * 256 + lane * 4;
    unsafeAtomicAdd(ap + 0, bf2f_lo(r.x));
    unsafeAtomicAdd(ap + 1, bf2f_hi(r.x));
    unsafeAtomicAdd(ap + 2, bf2f_lo(r.y));
    unsafeAtomicAdd(ap + 3, bf2f_hi(r.y));
}

__global__ __launch_bounds__(256) void k_cvt(
    const float* __restrict__ in, unsigned short* __restrict__ outb, int n)
{
    int i = blockIdx.x * 256 + threadIdx.x;
    if (i < n) outb[i] = f2bf(in[i]);
}

// ---------------- K4a: parallel reduce of partials ----------------
__global__ __launch_bounds__(256) void k_reduce(
    const float* __restrict__ partials, float* __restrict__ accum, int nblk)
{
    __shared__ float lsum[4][64];
    const int t = threadIdx.x & 63;
    const int w = threadIdx.x >> 6;
    float s = 0.f;
    for (int g = blockIdx.x * 4 + w; g < nblk; g += gridDim.x * 4)
        s += partials[(size_t)g * 64 + t];
    lsum[w][t] = s;
    __syncthreads();
    if (threadIdx.x < 64) {
        const float v = lsum[0][t] + lsum[1][t] + lsum[2][t] + lsum[3][t];
        unsafeAtomicAdd(&accum[t], v);
    }
}

// ---------------- K4b: apply layer3 to mean(h2) ----------------
__global__ __launch_bounds__(64) void k_final(
    const float* __restrict__ accum, const float* __restrict__ W3,
    const float* __restrict__ b3v, float* __restrict__ out)
{
    const int tid = threadIdx.x;
    if (tid < 2 * OO) {
        const int b = tid / OO, o = tid % OO;
        float acc = b3v[o];
        const float inv = 1.0f / (float)NN;
        #pragma unroll
        for (int j = 0; j < L2; ++j) acc += (accum[b * 32 + j] * inv) * W3[j * OO + o];
        out[tid] = acc;
    }
}

extern "C" void kernel_launch(void* const* d_in, const int* in_sizes, int n_in,
                              void* d_out, int out_size, void* d_ws, size_t ws_size,
                              hipStream_t stream) {
    const float* x  = (const float*)d_in[0];
    const int*   ei = (const int*)d_in[1];
    const float* W  = (const float*)d_in[2];
    const float* b0 = (const float*)d_in[3];
    const float* W1 = (const float*)d_in[4];
    const float* b1 = (const float*)d_in[5];
    const float* W2 = (const float*)d_in[6];
    const float* b2 = (const float*)d_in[7];
    const float* W3 = (const float*)d_in[8];
    const float* b3 = (const float*)d_in[9];
    float* out = (float*)d_out;

    const int E = in_sizes[1] / 2;           // 800000
    const int rows = 2 * NN;                 // 100000 storage rows
    const int nblk = (rows + 63) / 64;       // 1563 (mlp blocks)
    const int ntiles = (rows + 127) / 128;   // 782 (support tiles)
    const int nsb = (NN + 1023) / 1024;      // 49 scan blocks
    const int wpn = 128 * 136 + 64 * 136 + 32 * 72;   // prep elements

    // workspace layout — weight buffers before the int arrays (16-B aligned)
    unsigned short* supb = (unsigned short*)d_ws;                    // rows*HH bf16 (interleaved)
    unsigned short* aggb = supb + (size_t)rows * HH;                 // rows*HH bf16 (interleaved)
    float* partials = (float*)(aggb + (size_t)rows * HH);            // nblk*64
    float* accum    = partials + (size_t)nblk * 64;                  // 64
    unsigned short* wtb  = (unsigned short*)(accum + 64);            // 128*136
    unsigned short* w1tb = wtb + 128 * 136;                          // 64*136
    unsigned short* w2tb = w1tb + 64 * 136;                          // 32*72
    int*   counts   = (int*)(w2tb + 32 * 72);                        // NN
    int*   cursor   = counts + NN;                                   // NN
    int*   offsets  = cursor + NN;                                   // NN+1
    int*   blksum   = offsets + NN + 1;                              // 64
    int*   ss       = blksum + 64;                                   // E
    float* aggf     = (float*)(ss + E);                              // rows*HH (fallback only)
    const size_t need_csr = ((size_t)rows * HH * 2 + wpn) * sizeof(unsigned short)
                      + ((size_t)nblk * 64 + 64) * sizeof(float)
                      + ((size_t)NN * 3 + 1 + 64 + E) * sizeof(int);
    const size_t need_fb = need_csr + (size_t)rows * HH * sizeof(float);

    if (ws_size >= need_csr && nsb <= 64) {
        hipMemsetAsync(accum, 0, 64 * sizeof(float), stream);
        hipMemsetAsync(counts, 0, 2 * (size_t)NN * sizeof(int), stream);  // counts+cursor
        k_wprep<<<dim3((wpn + 255) / 256), dim3(256), 0, stream>>>(W, W1, W2, wtb, w1tb, w2tb);
        k_support<<<dim3(512), dim3(512), 0, stream>>>(x, wtb, supb, rows, ei, counts, E, ntiles);
        k_scan1<<<dim3(nsb), dim3(1024), 0, stream>>>(counts, offsets, blksum, NN);
        k_scan2<<<dim3(nsb), dim3(1024), 0, stream>>>(offsets, blksum, nsb, NN);
        k_bucket<<<dim3((E + 255) / 256), dim3(256), 0, stream>>>(ei, offsets, cursor, ss, E);
        k_agg<<<dim3((NN + 3) / 4), dim3(256), 0, stream>>>(supb, offsets, ss, aggb, NN);
        k_mlp<<<dim3(nblk), dim3(512), 0, stream>>>(aggb, b0, w1tb, b1, w2tb, b2, partials, rows);
    } else if (ws_size >= need_fb) {
        hipMemsetAsync(accum, 0, 64 * sizeof(float), stream);
        hipMemsetAsync(counts, 0, 2 * (size_t)NN * sizeof(int), stream);
        hipMemsetAsync(aggf, 0, (size_t)rows * HH * sizeof(float), stream);
        k_wprep<<<dim3((wpn + 255) / 256), dim3(256), 0, stream>>>(W, W1, W2, wtb, w1tb, w2tb);
        k_support<<<dim3(512), dim3(512), 0, stream>>>(x, wtb, supb, rows, ei, counts, 0, ntiles);
        k_scatter<<<dim3((E + 3) / 4), dim3(256), 0, stream>>>(ei, supb, aggf, E);
        k_cvt<<<dim3((rows * HH + 255) / 256), dim3(256), 0, stream>>>(aggf, aggb, rows * HH);
        k_mlp<<<dim3(nblk), dim3(512), 0, stream>>>(aggb, b0, w1tb, b1, w2tb, b2, partials, rows);
    }

    k_reduce<<<dim3(64), dim3(256), 0, stream>>>(partials, accum, nblk);
    k_final<<<dim3(1), dim3(64), 0, stream>>>(accum, W3, b3, out);
}

// Round 13
// 281.613 us; speedup vs baseline: 1.0047x; 1.0047x over previous
//
#include <hip/hip_runtime.h>
#include <math.h>

#define NN 50000
#define DD 128
#define HH 128
#define L1 64
#define L2 32
#define OO 10

typedef short v8s __attribute__((ext_vector_type(8)));   // 8 bf16 (4 VGPRs)
typedef float v4f __attribute__((ext_vector_type(4)));   // MFMA accumulator

// ---- bf16 helpers (manual: RNE pack) ----
__device__ __forceinline__ float bf2f_lo(unsigned u) { return __uint_as_float(u << 16); }
__device__ __forceinline__ float bf2f_hi(unsigned u) { return __uint_as_float(u & 0xffff0000u); }
__device__ __forceinline__ unsigned short f2bf(float f) {
    unsigned u = __float_as_uint(f);
    return (unsigned short)((u + 0x7fffu + ((u >> 16) & 1u)) >> 16);
}
__device__ __forceinline__ float gelu_f(float v) {
    return 0.5f * v * (1.f + erff(v * 0.70710678118654752f));
}

// ---------------- K0: weight transposes + workspace zeroing (fused memsets) ----
__global__ __launch_bounds__(256) void k_wprep(
    const float* __restrict__ W, const float* __restrict__ W1,
    const float* __restrict__ W2, unsigned short* __restrict__ wtb,
    unsigned short* __restrict__ w1tb, unsigned short* __restrict__ w2tb,
    int* __restrict__ zero_ints, int zn, float* __restrict__ accum)
{
    int i = blockIdx.x * 256 + threadIdx.x;
    if (i < 128 * 136) {
        int n = i / 136, k = i % 136;
        wtb[i] = (k < DD) ? f2bf(W[k * HH + n]) : (unsigned short)0;
    } else if (i < 128 * 136 + 64 * 136) {
        int j = i - 128 * 136;
        int n = j / 136, k = j % 136;
        w1tb[j] = (k < HH) ? f2bf(W1[k * L1 + n]) : (unsigned short)0;
    } else if (i < 128 * 136 + 64 * 136 + 32 * 72) {
        int j = i - (128 * 136 + 64 * 136);
        int n = j / 72, k = j % 72;
        w2tb[j] = (k < L1) ? f2bf(W2[k * L2 + n]) : (unsigned short)0;
    }
    if (i < 64) accum[i] = 0.f;
    for (int z = i; z < zn; z += gridDim.x * 256) zero_ints[z] = 0;
}

// ---------------- K1: support = x @ W via bf16 MFMA (LDS-staged operands) ------
// EMPIRICAL LAW (R10/R11 fails): MFMA operands must be LDS-staged on this
// toolchain. 64-row tiles: xs 17.4 KB + wt 34.8 KB = 52.2 KB -> 3 blk/CU,
// 24 waves/CU. wt staged once/block; grid-stride over tiles restages only xs.
// Wave w: rows (w&3)*16..+16, cols (w>>2)*64..+64 (4 ct). Bit-identical
// accumulation vs R12. Fused dst-histogram. Output interleaved (node*2+batch).
__global__ __launch_bounds__(512, 6) void k_support(
    const float* __restrict__ x, const unsigned short* __restrict__ wtb,
    unsigned short* __restrict__ supb, int rows,
    const int* __restrict__ ei, int* __restrict__ counts, int E, int ntiles)
{
    __shared__ __align__(16) unsigned short xs[64 * 136];
    __shared__ __align__(16) unsigned short wt[128 * 136];
    const int tid = threadIdx.x;

    // stage W^T once per block
    for (int u = tid * 4; u < 128 * 136; u += 2048)
        *(uint2*)(&wt[u]) = *(const uint2*)(wtb + u);

    // fused dst-histogram (independent; hides under staging/MFMA)
    {
        const int chunk = (E + gridDim.x - 1) / gridDim.x;
        const int e0 = blockIdx.x * chunk;
        const int e1 = min(e0 + chunk, E);
        for (int e = e0 + tid; e < e1; e += 512)
            atomicAdd(&counts[ei[(size_t)E + e]], 1);
    }

    const int lane = tid & 63;
    const int w = tid >> 6;        // wave 0..7
    const int m0 = (w & 3) * 16;   // row-tile base (tile-local)
    const int c0 = (w >> 2) * 64;  // col-half base
    const int lm = lane & 15;
    const int q  = lane >> 4;      // 0..3

    for (int t = blockIdx.x; t < ntiles; t += gridDim.x) {
        const int row0 = t * 64;
        __syncthreads();   // prev-tile xs consumed (orders wt on first iter)
        for (int u = tid * 4; u < 64 * DD; u += 2048) {
            const int r = u >> 7, c = u & 127;
            float4 v = make_float4(0.f, 0.f, 0.f, 0.f);
            if (row0 + r < rows) v = *(const float4*)(x + (size_t)(row0 + r) * DD + c);
            ushort4 o;
            o.x = f2bf(v.x); o.y = f2bf(v.y); o.z = f2bf(v.z); o.w = f2bf(v.w);
            *(ushort4*)(&xs[r * 136 + c]) = o;
        }
        __syncthreads();

        v4f acc[4];
        #pragma unroll
        for (int i = 0; i < 4; ++i) acc[i] = (v4f)(0.f);

        #pragma unroll
        for (int ks = 0; ks < 4; ++ks) {
            const int k0 = ks * 32 + q * 8;
            const v8s af = *(const v8s*)(&xs[(m0 + lm) * 136 + k0]);
            #pragma unroll
            for (int ct = 0; ct < 4; ++ct) {
                const v8s bf = *(const v8s*)(&wt[(c0 + ct * 16 + lm) * 136 + k0]);
                acc[ct] = __builtin_amdgcn_mfma_f32_16x16x32_bf16(af, bf, acc[ct], 0, 0, 0);
            }
        }

        // C/D: col = c0 + ct*16 + lm, row = q*4 + reg  [m89-verified]
        #pragma unroll
        for (int ct = 0; ct < 4; ++ct) {
            const int col = c0 + ct * 16 + lm;
            #pragma unroll
            for (int r = 0; r < 4; ++r) {
                const int rowg = row0 + m0 + q * 4 + r;
                if (rowg < rows) {
                    const int b = (rowg >= NN) ? 1 : 0;
                    const int n = rowg - b * NN;
                    supb[((size_t)n * 2 + b) * HH + col] = f2bf(acc[ct][r]);
                }
            }
        }
    }
}

// ---------------- multi-block scan, stage 1 ----------------
__global__ __launch_bounds__(1024) void k_scan1(
    const int* __restrict__ counts, int* __restrict__ offsets,
    int* __restrict__ blksum, int n)
{
    __shared__ int wsum[16], woff[16];
    const int tid = threadIdx.x, lane = tid & 63, wv = tid >> 6;
    const int i = blockIdx.x * 1024 + tid;
    int v = (i < n) ? counts[i] : 0;
    int x = v;
    #pragma unroll
    for (int d = 1; d < 64; d <<= 1) { int t = __shfl_up(x, d); if (lane >= d) x += t; }
    if (lane == 63) wsum[wv] = x;
    __syncthreads();
    if (wv == 0 && lane < 16) {
        int y = wsum[lane];
        #pragma unroll
        for (int d = 1; d < 16; d <<= 1) { int t = __shfl_up(y, d); if (lane >= d) y += t; }
        woff[lane] = y - wsum[lane];
        if (lane == 15) blksum[blockIdx.x] = y;
    }
    __syncthreads();
    if (i < n) offsets[i] = woff[wv] + (x - v);
}

// ---------------- multi-block scan, stage 2 ----------------
__global__ __launch_bounds__(1024) void k_scan2(
    int* __restrict__ offsets, const int* __restrict__ blksum, int nblk, int n)
{
    __shared__ int base_sh, tot_sh;
    const int tid = threadIdx.x, lane = tid & 63, wv = tid >> 6;
    if (wv == 0) {
        int v = (lane < nblk) ? blksum[lane] : 0;
        int x = v;
        #pragma unroll
        for (int d = 1; d < 64; d <<= 1) { int t = __shfl_up(x, d); if (lane >= d) x += t; }
        int incl = __shfl(x, blockIdx.x);
        int own  = __shfl(v, blockIdx.x);
        int tot  = __shfl(x, nblk - 1);
        if (lane == 0) { base_sh = incl - own; tot_sh = tot; }
    }
    __syncthreads();
    const int i = blockIdx.x * 1024 + tid;
    if (i < n) offsets[i] += base_sh;
    if (blockIdx.x == nblk - 1 && tid == 0) offsets[n] = tot_sh;
}

// ---------------- CSR build: bucket src indices by dst ----------------
__global__ __launch_bounds__(256) void k_bucket(
    const int* __restrict__ ei, const int* __restrict__ offsets,
    int* __restrict__ cursor, int* __restrict__ ss, int E)
{
    int e = blockIdx.x * 256 + threadIdx.x;
    if (e < E) {
        int d = ei[E + e];
        int pos = offsets[d] + atomicAdd(&cursor[d], 1);
        ss[pos] = ei[e];
    }
}

// ---------------- K2: gather-aggregate over interleaved bf16 rows -------------
__global__ __launch_bounds__(256) void k_agg(
    const unsigned short* __restrict__ supb, const int* __restrict__ offsets,
    const int* __restrict__ ss, unsigned short* __restrict__ aggb, int nn)
{
    const int tid = threadIdx.x;
    const int lane = tid & 63;
    const int wv = tid >> 6;
    const int d = blockIdx.x * 4 + wv;
    if (d >= nn) return;
    const unsigned short* sp = supb + lane * 4;
    const int s0 = offsets[d], s1 = offsets[d + 1];
    float4 a = make_float4(0.f, 0.f, 0.f, 0.f);
    float4 a2 = make_float4(0.f, 0.f, 0.f, 0.f);
    int i = s0;
    for (; i + 4 <= s1; i += 4) {
        const int sA = ss[i], sB = ss[i + 1], sC = ss[i + 2], sD = ss[i + 3];
        const uint2 rA = *(const uint2*)(sp + (size_t)sA * 256);
        const uint2 rB = *(const uint2*)(sp + (size_t)sB * 256);
        const uint2 rC = *(const uint2*)(sp + (size_t)sC * 256);
        const uint2 rD = *(const uint2*)(sp + (size_t)sD * 256);
        a.x  += bf2f_lo(rA.x); a.y  += bf2f_hi(rA.x); a.z  += bf2f_lo(rA.y); a.w  += bf2f_hi(rA.y);
        a2.x += bf2f_lo(rB.x); a2.y += bf2f_hi(rB.x); a2.z += bf2f_lo(rB.y); a2.w += bf2f_hi(rB.y);
        a.x  += bf2f_lo(rC.x); a.y  += bf2f_hi(rC.x); a.z  += bf2f_lo(rC.y); a.w  += bf2f_hi(rC.y);
        a2.x += bf2f_lo(rD.x); a2.y += bf2f_hi(rD.x); a2.z += bf2f_lo(rD.y); a2.w += bf2f_hi(rD.y);
    }
    for (; i < s1; ++i) {
        const uint2 r = *(const uint2*)(sp + (size_t)ss[i] * 256);
        a.x += bf2f_lo(r.x); a.y += bf2f_hi(r.x); a.z += bf2f_lo(r.y); a.w += bf2f_hi(r.y);
    }
    a.x += a2.x; a.y += a2.y; a.z += a2.z; a.w += a2.w;
    ushort4 o;
    o.x = f2bf(a.x); o.y = f2bf(a.y); o.z = f2bf(a.z); o.w = f2bf(a.w);
    *(ushort4*)(aggb + (size_t)d * 256 + lane * 4) = o;
}

// ---------------- K3: gelu + MFMA MLP(128->64->32) + column sums --------------
__global__ __launch_bounds__(512, 6) void k_mlp(
    const unsigned short* __restrict__ aggb, const float* __restrict__ b0v,
    const unsigned short* __restrict__ w1tb, const float* __restrict__ b1v,
    const unsigned short* __restrict__ w2tb, const float* __restrict__ b2v,
    float* __restrict__ partials, int srows)
{
    __shared__ __align__(16) unsigned short wt1[64 * 136];
    __shared__ __align__(16) unsigned short wt2[32 * 72];
    __shared__ __align__(16) unsigned char upool[64 * 136 * 2];
    __shared__ __align__(16) unsigned short h1b[64 * 72];
    __shared__ float b0s[DD], b1s[L1], b2s[L2];
    __shared__ float oacc[64];
    unsigned short* hsb = (unsigned short*)upool;   // [64][136] bf16
    float* h2p = (float*)upool;                     // [64][36] f32 (after hsb dead)

    const int tid = threadIdx.x;
    const int row0 = blockIdx.x * 64;

    for (int u = tid * 4; u < 64 * 136; u += 2048)
        *(uint2*)(&wt1[u]) = *(const uint2*)(w1tb + u);
    for (int u = tid * 4; u < 32 * 72; u += 2048)
        *(uint2*)(&wt2[u]) = *(const uint2*)(w2tb + u);
    if (tid < DD) b0s[tid] = b0v[tid];
    if (tid < L1) b1s[tid] = b1v[tid];
    if (tid < L2) b2s[tid] = b2v[tid];
    if (tid < 64) oacc[tid] = 0.f;

    for (int u = tid * 8; u < 64 * DD; u += 4096) {
        const int r = u >> 7, c = u & 127;
        uint4 raw = make_uint4(0, 0, 0, 0);
        if (row0 + r < srows) raw = *(const uint4*)(aggb + (size_t)(row0 + r) * HH + c);
        float v[8];
        v[0] = bf2f_lo(raw.x) + b0s[c + 0]; v[1] = bf2f_hi(raw.x) + b0s[c + 1];
        v[2] = bf2f_lo(raw.y) + b0s[c + 2]; v[3] = bf2f_hi(raw.y) + b0s[c + 3];
        v[4] = bf2f_lo(raw.z) + b0s[c + 4]; v[5] = bf2f_hi(raw.z) + b0s[c + 5];
        v[6] = bf2f_lo(raw.w) + b0s[c + 6]; v[7] = bf2f_hi(raw.w) + b0s[c + 7];
        ushort4 o0, o1;
        o0.x = f2bf(gelu_f(v[0])); o0.y = f2bf(gelu_f(v[1]));
        o0.z = f2bf(gelu_f(v[2])); o0.w = f2bf(gelu_f(v[3]));
        o1.x = f2bf(gelu_f(v[4])); o1.y = f2bf(gelu_f(v[5]));
        o1.z = f2bf(gelu_f(v[6])); o1.w = f2bf(gelu_f(v[7]));
        *(ushort4*)(&hsb[r * 136 + c]) = o0;
        *(ushort4*)(&hsb[r * 136 + c + 4]) = o1;
    }
    __syncthreads();

    const int lane = tid & 63;
    const int w = tid >> 6;
    const int lm = lane & 15;
    const int q = lane >> 4;
    const int r1 = (w & 3) * 16;

    // layer1 (64x128 @ 128x64)
    {
        const int c1 = (w >> 2) * 32;
        v4f a1[2];
        a1[0] = (v4f)(0.f); a1[1] = (v4f)(0.f);
        #pragma unroll
        for (int ks = 0; ks < 4; ++ks) {
            const int k0 = ks * 32 + q * 8;
            const v8s af = *(const v8s*)(&hsb[(r1 + lm) * 136 + k0]);
            #pragma unroll
            for (int ct = 0; ct < 2; ++ct) {
                const v8s bf = *(const v8s*)(&wt1[(c1 + ct * 16 + lm) * 136 + k0]);
                a1[ct] = __builtin_amdgcn_mfma_f32_16x16x32_bf16(af, bf, a1[ct], 0, 0, 0);
            }
        }
        #pragma unroll
        for (int ct = 0; ct < 2; ++ct) {
            const int col = c1 + ct * 16 + lm;
            const float bias = b1s[col];
            #pragma unroll
            for (int r = 0; r < 4; ++r)
                h1b[(r1 + q * 4 + r) * 72 + col] = f2bf(fmaxf(a1[ct][r] + bias, 0.f));
        }
    }
    __syncthreads();

    // layer2 (64x64 @ 64x32)
    {
        const int c2 = (w >> 2) * 16;
        v4f a2 = (v4f)(0.f);
        #pragma unroll
        for (int ks = 0; ks < 2; ++ks) {
            const int k0 = ks * 32 + q * 8;
            const v8s af = *(const v8s*)(&h1b[(r1 + lm) * 72 + k0]);
            const v8s bf = *(const v8s*)(&wt2[(c2 + lm) * 72 + k0]);
            a2 = __builtin_amdgcn_mfma_f32_16x16x32_bf16(af, bf, a2, 0, 0, 0);
        }
        const int col = c2 + lm;
        const float bias = b2s[col];
        #pragma unroll
        for (int r = 0; r < 4; ++r)
            h2p[(r1 + q * 4 + r) * 36 + col] = fmaxf(a2[r] + bias, 0.f);
    }
    __syncthreads();

    // column sums: storage row r -> batch r&1
    {
        const int c = tid & 31;
        const int g = tid >> 5;
        float p0 = 0.f, p1 = 0.f;
        #pragma unroll
        for (int i = 0; i < 4; ++i) {
            const int r = g * 4 + i;
            if (row0 + r < srows) {
                const float v = h2p[r * 36 + c];
                if (r & 1) p1 += v; else p0 += v;
            }
        }
        if (p0 != 0.f) atomicAdd(&oacc[c], p0);
        if (p1 != 0.f) atomicAdd(&oacc[32 + c], p1);
    }
    __syncthreads();
    if (tid < 64) partials[(size_t)blockIdx.x * 64 + tid] = oacc[tid];
}

// ---------------- Fallback path (ws too small for CSR) ----------------
__global__ __launch_bounds__(256) void k_scatter(
    const int* __restrict__ ei, const unsigned short* __restrict__ supb,
    float* __restrict__ aggf, int E)
{
    const int tid = threadIdx.x;
    const int eg = tid >> 6;
    const int lane = tid & 63;
    const int e = blockIdx.x * 4 + eg;
    if (e >= E) return;
    const int src = ei[e];
    const int dst = ei[E + e];
    const uint2 r = *(const uint2*)(supb + (size_t)src * 256 + lane * 4);
    float* ap = aggf + (size_t)dst * 256 + lane * 4;
    unsafeAtomicAdd(ap + 0, bf2f_lo(r.x));
    unsafeAtomicAdd(ap + 1, bf2f_hi(r.x));
    unsafeAtomicAdd(ap + 2, bf2f_lo(r.y));
    unsafeAtomicAdd(ap + 3, bf2f_hi(r.y));
}

__global__ __launch_bounds__(256) void k_cvt(
    const float* __restrict__ in, unsigned short* __restrict__ outb, int n)
{
    int i = blockIdx.x * 256 + threadIdx.x;
    if (i < n) outb[i] = f2bf(in[i]);
}

// ---------------- K4a: parallel reduce of partials ----------------
__global__ __launch_bounds__(256) void k_reduce(
    const float* __restrict__ partials, float* __restrict__ accum, int nblk)
{
    __shared__ float lsum[4][64];
    const int t = threadIdx.x & 63;
    const int w = threadIdx.x >> 6;
    float s = 0.f;
    for (int g = blockIdx.x * 4 + w; g < nblk; g += gridDim.x * 4)
        s += partials[(size_t)g * 64 + t];
    lsum[w][t] = s;
    __syncthreads();
    if (threadIdx.x < 64) {
        const float v = lsum[0][t] + lsum[1][t] + lsum[2][t] + lsum[3][t];
        unsafeAtomicAdd(&accum[t], v);
    }
}

// ---------------- K4b: apply layer3 to mean(h2) ----------------
__global__ __launch_bounds__(64) void k_final(
    const float* __restrict__ accum, const float* __restrict__ W3,
    const float* __restrict__ b3v, float* __restrict__ out)
{
    const int tid = threadIdx.x;
    if (tid < 2 * OO) {
        const int b = tid / OO, o = tid % OO;
        float acc = b3v[o];
        const float inv = 1.0f / (float)NN;
        #pragma unroll
        for (int j = 0; j < L2; ++j) acc += (accum[b * 32 + j] * inv) * W3[j * OO + o];
        out[tid] = acc;
    }
}

extern "C" void kernel_launch(void* const* d_in, const int* in_sizes, int n_in,
                              void* d_out, int out_size, void* d_ws, size_t ws_size,
                              hipStream_t stream) {
    const float* x  = (const float*)d_in[0];
    const int*   ei = (const int*)d_in[1];
    const float* W  = (const float*)d_in[2];
    const float* b0 = (const float*)d_in[3];
    const float* W1 = (const float*)d_in[4];
    const float* b1 = (const float*)d_in[5];
    const float* W2 = (const float*)d_in[6];
    const float* b2 = (const float*)d_in[7];
    const float* W3 = (const float*)d_in[8];
    const float* b3 = (const float*)d_in[9];
    float* out = (float*)d_out;

    const int E = in_sizes[1] / 2;           // 800000
    const int rows = 2 * NN;                 // 100000 storage rows
    const int nblk = (rows + 63) / 64;       // 1563 (mlp blocks, support tiles)
    const int nsb = (NN + 1023) / 1024;      // 49 scan blocks
    const int wpn = 128 * 136 + 64 * 136 + 32 * 72;   // prep elements

    // workspace layout — weight buffers before the int arrays (16-B aligned)
    unsigned short* supb = (unsigned short*)d_ws;                    // rows*HH bf16 (interleaved)
    unsigned short* aggb = supb + (size_t)rows * HH;                 // rows*HH bf16 (interleaved)
    float* partials = (float*)(aggb + (size_t)rows * HH);            // nblk*64
    float* accum    = partials + (size_t)nblk * 64;                  // 64
    unsigned short* wtb  = (unsigned short*)(accum + 64);            // 128*136
    unsigned short* w1tb = wtb + 128 * 136;                          // 64*136
    unsigned short* w2tb = w1tb + 64 * 136;                          // 32*72
    int*   counts   = (int*)(w2tb + 32 * 72);                        // NN
    int*   cursor   = counts + NN;                                   // NN
    int*   offsets  = cursor + NN;                                   // NN+1
    int*   blksum   = offsets + NN + 1;                              // 64
    int*   ss       = blksum + 64;                                   // E
    float* aggf     = (float*)(ss + E);                              // rows*HH (fallback only)
    const size_t need_csr = ((size_t)rows * HH * 2 + wpn) * sizeof(unsigned short)
                      + ((size_t)nblk * 64 + 64) * sizeof(float)
                      + ((size_t)NN * 3 + 1 + 64 + E) * sizeof(int);
    const size_t need_fb = need_csr + (size_t)rows * HH * sizeof(float);

    if (ws_size >= need_csr && nsb <= 64) {
        // wprep also zeroes counts+cursor (contiguous 2*NN ints) and accum
        k_wprep<<<dim3(256), dim3(256), 0, stream>>>(W, W1, W2, wtb, w1tb, w2tb,
                                                     counts, 2 * NN, accum);
        k_support<<<dim3(512), dim3(512), 0, stream>>>(x, wtb, supb, rows, ei, counts, E, nblk);
        k_scan1<<<dim3(nsb), dim3(1024), 0, stream>>>(counts, offsets, blksum, NN);
        k_scan2<<<dim3(nsb), dim3(1024), 0, stream>>>(offsets, blksum, nsb, NN);
        k_bucket<<<dim3((E + 255) / 256), dim3(256), 0, stream>>>(ei, offsets, cursor, ss, E);
        k_agg<<<dim3((NN + 3) / 4), dim3(256), 0, stream>>>(supb, offsets, ss, aggb, NN);
        k_mlp<<<dim3(nblk), dim3(512), 0, stream>>>(aggb, b0, w1tb, b1, w2tb, b2, partials, rows);
    } else if (ws_size >= need_fb) {
        k_wprep<<<dim3(256), dim3(256), 0, stream>>>(W, W1, W2, wtb, w1tb, w2tb,
                                                     counts, 2 * NN, accum);
        hipMemsetAsync(aggf, 0, (size_t)rows * HH * sizeof(float), stream);
        k_support<<<dim3(512), dim3(512), 0, stream>>>(x, wtb, supb, rows, ei, counts, 0, nblk);
        k_scatter<<<dim3((E + 3) / 4), dim3(256), 0, stream>>>(ei, supb, aggf, E);
        k_cvt<<<dim3((rows * HH + 255) / 256), dim3(256), 0, stream>>>(aggf, aggb, rows * HH);
        k_mlp<<<dim3(nblk), dim3(512), 0, stream>>>(aggb, b0, w1tb, b1, w2tb, b2, partials, rows);
    }

    k_reduce<<<dim3(64), dim3(256), 0, stream>>>(partials, accum, nblk);
    k_final<<<dim3(1), dim3(64), 0, stream>>>(accum, W3, b3, out);
}